// Round 6
// baseline (812.511 us; speedup 1.0000x reference)
//
#include <hip/hip_runtime.h>

#define BB 32
#define NSTEP 31
#define CROW 1040
#define CB_STRIDE 266240L   // 1040*256 (Q f32 per-b stride)
#define PPART 524288L       // 32*64*256 per projection part

__device__ __constant__ int d_lens[NSTEP] = {63,62,61,60,59,58,57,56,55,54,53,52,51,50,49,
                                             24,23,22,21,20,19,18,17,
                                             8,7,6,5,4,3,2,1};
__device__ __constant__ int d_cb[NSTEP] = {0,63,125,186,246,305,363,420,476,531,585,638,690,741,791,
                                           840,864,887,909,930,950,969,987,
                                           1004,1012,1019,1025,1030,1034,1037,1039};

typedef short v8s __attribute__((ext_vector_type(8)));
typedef float v4f __attribute__((ext_vector_type(4)));

__device__ __forceinline__ unsigned short rne_bf16(float f) {
    unsigned int u = __float_as_uint(f);
    u = (u + 0x7FFFu + ((u >> 16) & 1u)) >> 16;
    return (unsigned short)u;
}

// One-shot dtype/layout prep:
//  xb [32][64][256]   bf16 <- x[32][256][64]       (time-major transpose)
//  w2t[29*256][2][256] bf16 <- w2[29*256][256][2]  (k-major transpose)
//  w3t[2*256][3][256]  bf16 <- w3[2*256][256][3]
//  vwb[256][768]       bf16 <- vw
__global__ __launch_bounds__(256)
void prep(const float* __restrict__ x, const float* __restrict__ w2,
          const float* __restrict__ w3, const float* __restrict__ vw,
          unsigned short* __restrict__ xb, unsigned short* __restrict__ w2t,
          unsigned short* __restrict__ w3t, unsigned short* __restrict__ vwb)
{
    long idx = (long)blockIdx.x * 256 + threadIdx.x;
    if (idx < 524288) {                       // xb
        const int ci = idx & 255, l = (idx >> 8) & 63, b = (int)(idx >> 14);
        xb[idx] = rne_bf16(x[((long)b << 14) + ((long)ci << 6) + l]);
        return;
    }
    idx -= 524288;
    if (idx < 3801088) {                      // w2t
        const int ci = idx & 255, k = (idx >> 8) & 1; const long row = idx >> 9;
        w2t[idx] = rne_bf16(w2[row * 512 + ci * 2 + k]);
        return;
    }
    idx -= 3801088;
    if (idx < 393216) {                       // w3t
        const int ci = idx & 255; const long r = idx >> 8;
        const int k = (int)(r % 3); const long row = r / 3;
        w3t[idx] = rne_bf16(w3[row * 768 + ci * 3 + k]);
        return;
    }
    idx -= 393216;
    if (idx < 196608) vwb[idx] = rne_bf16(vw[idx]);
}

// ---- fused persistent chain: 1 block per batch element -------------------
// LDS activation tiles: [64 rows][256 ch] bf16, XOR-swizzled:
//   byte(row, elem_byte) = row*512 + (elem_byte ^ ((row&7)<<4))
// All LDS accesses are 8B/16B aligned so the XOR (bits 4..6) is consistent.

template<int KC, int S>
__device__ __forceinline__ void conv_step(
    const unsigned short* __restrict__ Wt, const float* __restrict__ bias,
    const char* __restrict__ in, char* __restrict__ out,
    int L, int wave, int nl, int g)
{
    const int nt = (L + 15) >> 4;
    v4f acc[4] = {{0,0,0,0},{0,0,0,0},{0,0,0,0},{0,0,0,0}};
    int lv[4];
    #pragma unroll
    for (int j = 0; j < 4; ++j) lv[j] = min(j * 16 + nl, L - 1);

    const unsigned short* Arow = Wt + (size_t)(wave * 16 + nl) * (KC * 256) + g * 8;
    #pragma unroll
    for (int ki = 0; ki < KC * 8; ++ki) {
        const int kk = ki * 32;
        const v8s af = *(const v8s*)(Arow + kk);
        #pragma unroll
        for (int j = 0; j < 4; ++j) {
            if (j < nt) {
                const int ir = lv[j] * S + (kk >> 8);
                const v8s bf = *(const v8s*)(in + ir * 512 +
                                (((kk & 255) * 2 + g * 16) ^ ((ir & 7) << 4)));
                acc[j] = __builtin_amdgcn_mfma_f32_16x16x32_bf16(af, bf, acc[j], 0, 0, 0);
            }
        }
    }
    const int m0 = wave * 16 + g * 4;
    const float4 bv = *(const float4*)(bias + m0);
    #pragma unroll
    for (int j = 0; j < 4; ++j) {
        const int l = j * 16 + nl;
        if (j < nt && l < L) {
            ushort4 pk;
            pk.x = rne_bf16(acc[j][0] + bv.x);
            pk.y = rne_bf16(acc[j][1] + bv.y);
            pk.z = rne_bf16(acc[j][2] + bv.z);
            pk.w = rne_bf16(acc[j][3] + bv.w);
            *(ushort4*)(out + l * 512 + ((m0 * 2) ^ ((l & 7) << 4))) = pk;
        }
    }
}

__device__ __forceinline__ void q_step(
    const unsigned short* __restrict__ vwb,
    const char* __restrict__ act, float* __restrict__ Qf,
    int b, int row0, int L, int wave, int nl, int g)
{
    const int nt = (L + 15) >> 4;
    v4f acc[4] = {{0,0,0,0},{0,0,0,0},{0,0,0,0},{0,0,0,0}};
    int lv[4];
    #pragma unroll
    for (int j = 0; j < 4; ++j) lv[j] = min(j * 16 + nl, L - 1);

    const unsigned short* Arow = vwb + (size_t)(wave * 16 + nl) * 768 + 256 + g * 8;
    #pragma unroll
    for (int ki = 0; ki < 8; ++ki) {
        const int kk = ki * 32;
        const v8s af = *(const v8s*)(Arow + kk);
        #pragma unroll
        for (int j = 0; j < 4; ++j) {
            if (j < nt) {
                const int ir = lv[j];
                const v8s bf = *(const v8s*)(act + ir * 512 +
                                ((kk * 2 + g * 16) ^ ((ir & 7) << 4)));
                acc[j] = __builtin_amdgcn_mfma_f32_16x16x32_bf16(af, bf, acc[j], 0, 0, 0);
            }
        }
    }
    const int m0 = wave * 16 + g * 4;
    #pragma unroll
    for (int j = 0; j < 4; ++j) {
        const int l = j * 16 + nl;
        if (j < nt && l < L)
            *(v4f*)(Qf + (size_t)b * CB_STRIDE + (size_t)(row0 + l) * 256 + m0) = acc[j];
    }
}

__global__ __launch_bounds__(1024, 4)
void chain(const unsigned short* __restrict__ xb,
           const unsigned short* __restrict__ w2t,
           const unsigned short* __restrict__ w3t,
           const unsigned short* __restrict__ vwb,
           const float* __restrict__ b2, const float* __restrict__ b3,
           float* __restrict__ Qf, float* __restrict__ P)
{
    __shared__ unsigned short lds[2][64][256];
    const int b = blockIdx.x;
    const int tid = threadIdx.x;
    const int wave = tid >> 6, lane = tid & 63, nl = lane & 15, g = lane >> 4;

    char* base = (char*)&lds[0][0][0];   // single LDS base; ping-pong via offset

    // stage x into buf0 (swizzled)
    {
        const unsigned short* src = xb + (size_t)b * 16384;
        #pragma unroll
        for (int i = 0; i < 2; ++i) {
            const int c = tid + i * 1024;
            const int r = c >> 5, cc = c & 31;
            const v8s v = *(const v8s*)(src + r * 256 + cc * 8);
            *(v8s*)(base + r * 512 + ((cc * 16) ^ ((r & 7) << 4))) = v;
        }
    }
    __syncthreads();

    // projections P[p][b][o][i] = vw[:, p*256 : p*256+256] * x
    {
        const char* in = base;
        for (int p = 0; p < 3; ++p) {
            v4f acc[4] = {{0,0,0,0},{0,0,0,0},{0,0,0,0},{0,0,0,0}};
            #pragma unroll
            for (int ki = 0; ki < 8; ++ki) {
                const int kk = ki * 32;
                const v8s af = *(const v8s*)(vwb + (size_t)(wave * 16 + nl) * 768 + p * 256 + kk + g * 8);
                #pragma unroll
                for (int j = 0; j < 4; ++j) {
                    const int l = j * 16 + nl;
                    const v8s bf = *(const v8s*)(in + l * 512 +
                                    ((kk * 2 + g * 16) ^ ((l & 7) << 4)));
                    acc[j] = __builtin_amdgcn_mfma_f32_16x16x32_bf16(af, bf, acc[j], 0, 0, 0);
                }
            }
            const int m0 = wave * 16 + g * 4;
            #pragma unroll
            for (int j = 0; j < 4; ++j) {
                float* po = P + (size_t)p * PPART + (size_t)b * 16384 + j * 16 + nl;
                #pragma unroll
                for (int r = 0; r < 4; ++r) po[(size_t)(m0 + r) * 64] = acc[j][r];
            }
        }
    }

    // 31-step chain, ping-pong LDS buffers; Q segment after each step
    int cur = 0, i2 = 0, i3 = 0;
    for (int t = 0; t < NSTEP; ++t) {
        const int L = d_lens[t];
        char* inb  = base + cur * 32768;
        char* outb = base + (cur ^ 1) * 32768;
        if (t == 15 || t == 23) {
            conv_step<3, 2>(w3t + (size_t)i3 * 196608, b3 + i3 * 256,
                            inb, outb, L, wave, nl, g);
            ++i3;
        } else {
            conv_step<2, 1>(w2t + (size_t)i2 * 131072, b2 + i2 * 256,
                            inb, outb, L, wave, nl, g);
            ++i2;
        }
        __syncthreads();
        q_step(vwb, outb, Qf, b, d_cb[t], L, wave, nl, g);
        cur ^= 1;
    }
}

// out[b,o,i,j] = vis_b[o]                          (unset)
//             + Pl[b,o,i]+Pm[b,o,i]+Pr[b,o,i]      (diag)
//             + Pl[b,o,i]+Q[b,q,o]+Pr[b,o,j]       (set off-diag)
__global__ __launch_bounds__(256)
void final_k(const float* __restrict__ P, const float* __restrict__ Qb,
             const float* __restrict__ vb, float* __restrict__ out)
{
    const int b = blockIdx.x >> 6;
    const int i = blockIdx.x & 63;
    const int t = threadIdx.x;
    const int j = t & 63;
    const int os = t >> 6;

    __shared__ int qidx[64];
    if (t < 64) {
        const int d = t - i;
        int v = -1;
        if (t == i) v = -2;
        else if (d >= 1 && d <= 15) v = d_cb[d-1] + i;
        else if (d >= 17 && d <= 31 && (d & 1) && !(i & 1)) v = d_cb[15 + ((d-17)>>1)] + (i>>1);
        else if (d >= 35 && d <= 63 && ((d-35)&3)==0 && !(i&3)) v = d_cb[23 + ((d-35)>>2)] + (i>>2);
        qidx[t] = v;
    }
    __syncthreads();
    const int q = qidx[j];

    for (int oc = 0; oc < 64; ++oc) {
        const int o = oc * 4 + os;
        const float pl = P[(size_t)(b * 256 + o) * 64 + i];
        const float pm = P[524288u + (size_t)(b * 256 + o) * 64 + i];
        const float* pr = P + 1048576u + (size_t)(b * 256 + o) * 64;
        const float vbv = vb[o];
        float v;
        if (q == -2)      v = pl + pm + pr[i] + vbv;
        else if (q >= 0)  v = pl + Qb[(size_t)b * CB_STRIDE + (size_t)q * 256 + o] + pr[j] + vbv;
        else              v = vbv;
        out[(((size_t)b * 256 + o) * 64 + i) * 64 + j] = v;
    }
}

extern "C" void kernel_launch(void* const* d_in, const int* in_sizes, int n_in,
                              void* d_out, int out_size, void* d_ws, size_t ws_size,
                              hipStream_t stream)
{
    const float* x   = (const float*)d_in[0];
    const float* w2  = (const float*)d_in[1];
    const float* b2  = (const float*)d_in[2];
    const float* w3  = (const float*)d_in[3];
    const float* b3  = (const float*)d_in[4];
    const float* vw  = (const float*)d_in[5];
    const float* vb  = (const float*)d_in[6];
    float* out = (float*)d_out;

    // workspace: Q f32 34.08M | P f32 6.29M | xb 1.05M | w2t 7.60M | w3t 0.79M | vwb 0.39M
    char* w = (char*)d_ws;
    float*          Qf  = (float*)w;          w += (size_t)BB * CB_STRIDE * 4;
    float*          P   = (float*)w;          w += (size_t)3 * PPART * 4;
    unsigned short* xb  = (unsigned short*)w; w += (size_t)BB * 16384 * 2;
    unsigned short* w2t = (unsigned short*)w; w += (size_t)29 * 131072 * 2;
    unsigned short* w3t = (unsigned short*)w; w += (size_t)2 * 196608 * 2;
    unsigned short* vwb = (unsigned short*)w;

    prep<<<dim3(19200), 256, 0, stream>>>(x, w2, w3, vw, xb, w2t, w3t, vwb);
    chain<<<dim3(BB), 1024, 0, stream>>>(xb, w2t, w3t, vwb, b2, b3, Qf, P);
    final_k<<<dim3(BB * 64), 256, 0, stream>>>(P, Qf, vb, out);
}

// Round 7
// 549.436 us; speedup vs baseline: 1.4788x; 1.4788x over previous
//
#include <hip/hip_runtime.h>

#define BB 32
#define NSTEP 31
#define CROW 1040
#define CB_STRIDE 266240L   // 1040*256 (Q f32 per-b stride)
#define PPART 524288L       // 32*64*256 per projection part
#define RS 528              // LDS row stride in bytes (264 shorts; 132 dwords, %32=4 -> 2-way max)
#define BUF (64 * RS)       // one activation buffer: 33792 B

__device__ __constant__ int d_lens[NSTEP] = {63,62,61,60,59,58,57,56,55,54,53,52,51,50,49,
                                             24,23,22,21,20,19,18,17,
                                             8,7,6,5,4,3,2,1};
__device__ __constant__ int d_cb[NSTEP] = {0,63,125,186,246,305,363,420,476,531,585,638,690,741,791,
                                           840,864,887,909,930,950,969,987,
                                           1004,1012,1019,1025,1030,1034,1037,1039};

typedef short v8s __attribute__((ext_vector_type(8)));
typedef float v4f __attribute__((ext_vector_type(4)));

__device__ __forceinline__ unsigned short rne_bf16(float f) {
    unsigned int u = __float_as_uint(f);
    u = (u + 0x7FFFu + ((u >> 16) & 1u)) >> 16;
    return (unsigned short)u;
}

// One-shot dtype/layout prep:
//  xb [32][64][256]    bf16 <- x[32][256][64]      (time-major transpose)
//  w2t[29*256][2][256] bf16 <- w2[29*256][256][2]  (k-major transpose)
//  w3t[2*256][3][256]  bf16 <- w3[2*256][256][3]
//  vwb[256][768]       bf16 <- vw
__global__ __launch_bounds__(256)
void prep(const float* __restrict__ x, const float* __restrict__ w2,
          const float* __restrict__ w3, const float* __restrict__ vw,
          unsigned short* __restrict__ xb, unsigned short* __restrict__ w2t,
          unsigned short* __restrict__ w3t, unsigned short* __restrict__ vwb)
{
    long idx = (long)blockIdx.x * 256 + threadIdx.x;
    if (idx < 524288) {                       // xb
        const int ci = idx & 255, l = (idx >> 8) & 63, b = (int)(idx >> 14);
        xb[idx] = rne_bf16(x[((long)b << 14) + ((long)ci << 6) + l]);
        return;
    }
    idx -= 524288;
    if (idx < 3801088) {                      // w2t
        const int ci = idx & 255, k = (idx >> 8) & 1; const long row = idx >> 9;
        w2t[idx] = rne_bf16(w2[row * 512 + ci * 2 + k]);
        return;
    }
    idx -= 3801088;
    if (idx < 393216) {                       // w3t
        const int ci = idx & 255; const long r = idx >> 8;
        const int k = (int)(r % 3); const long row = r / 3;
        w3t[idx] = rne_bf16(w3[row * 768 + ci * 3 + k]);
        return;
    }
    idx -= 393216;
    if (idx < 196608) vwb[idx] = rne_bf16(vw[idx]);
}

// ---- fused persistent chain: 1 block (16 waves) per batch element --------
// LDS activation tiles: [64 rows][256 ch] bf16, row stride RS=528 bytes.
// Element (row, ci) at byte row*RS + ci*2. MFMA bf fragment for (l, ki):
//   addr = (l*S + (ki>>3))*RS + (ki&7)*64 + g*16   -- ki*64 is an immediate.

template<int KC, int S>
__device__ __forceinline__ void conv_step(
    const unsigned short* __restrict__ Wt, const float* __restrict__ bias,
    const char* in, char* out, int L, int wave, int nl, int g)
{
    const int nt = (L + 15) >> 4;
    v4f acc[4] = {{0,0,0,0},{0,0,0,0},{0,0,0,0},{0,0,0,0}};
    int lv[4];
    #pragma unroll
    for (int j = 0; j < 4; ++j) lv[j] = min(j * 16 + nl, L - 1);

    const unsigned short* Arow = Wt + (size_t)(wave * 16 + nl) * (KC * 256) + g * 8;

    #pragma unroll
    for (int c = 0; c < KC; ++c) {
        v8s afs[8];
        #pragma unroll
        for (int k = 0; k < 8; ++k)
            afs[k] = *(const v8s*)(Arow + (c * 8 + k) * 32);
        const char* rp0 = in + (lv[0] * S + c) * RS + g * 16;
        const char* rp1 = in + (lv[1] * S + c) * RS + g * 16;
        const char* rp2 = in + (lv[2] * S + c) * RS + g * 16;
        const char* rp3 = in + (lv[3] * S + c) * RS + g * 16;
        #pragma unroll
        for (int k = 0; k < 8; ++k) {
            acc[0] = __builtin_amdgcn_mfma_f32_16x16x32_bf16(afs[k], *(const v8s*)(rp0 + k * 64), acc[0], 0, 0, 0);
            if (nt > 1) acc[1] = __builtin_amdgcn_mfma_f32_16x16x32_bf16(afs[k], *(const v8s*)(rp1 + k * 64), acc[1], 0, 0, 0);
            if (nt > 2) acc[2] = __builtin_amdgcn_mfma_f32_16x16x32_bf16(afs[k], *(const v8s*)(rp2 + k * 64), acc[2], 0, 0, 0);
            if (nt > 3) acc[3] = __builtin_amdgcn_mfma_f32_16x16x32_bf16(afs[k], *(const v8s*)(rp3 + k * 64), acc[3], 0, 0, 0);
        }
    }
    const int m0 = wave * 16 + g * 4;
    const float4 bv = *(const float4*)(bias + m0);
    #pragma unroll
    for (int j = 0; j < 4; ++j) {
        const int l = j * 16 + nl;
        if (j < nt && l < L) {
            ushort4 pk;
            pk.x = rne_bf16(acc[j][0] + bv.x);
            pk.y = rne_bf16(acc[j][1] + bv.y);
            pk.z = rne_bf16(acc[j][2] + bv.z);
            pk.w = rne_bf16(acc[j][3] + bv.w);
            *(ushort4*)(out + l * RS + m0 * 2) = pk;
        }
    }
}

__device__ __forceinline__ void q_step(
    const unsigned short* __restrict__ vwb,
    const char* act, float* __restrict__ Qf,
    int b, int row0, int L, int wave, int nl, int g)
{
    const int nt = (L + 15) >> 4;
    v4f acc[4] = {{0,0,0,0},{0,0,0,0},{0,0,0,0},{0,0,0,0}};
    int lv[4];
    #pragma unroll
    for (int j = 0; j < 4; ++j) lv[j] = min(j * 16 + nl, L - 1);

    const unsigned short* Arow = vwb + (size_t)(wave * 16 + nl) * 768 + 256 + g * 8;
    v8s afs[8];
    #pragma unroll
    for (int k = 0; k < 8; ++k)
        afs[k] = *(const v8s*)(Arow + k * 32);
    const char* rp0 = act + lv[0] * RS + g * 16;
    const char* rp1 = act + lv[1] * RS + g * 16;
    const char* rp2 = act + lv[2] * RS + g * 16;
    const char* rp3 = act + lv[3] * RS + g * 16;
    #pragma unroll
    for (int k = 0; k < 8; ++k) {
        acc[0] = __builtin_amdgcn_mfma_f32_16x16x32_bf16(afs[k], *(const v8s*)(rp0 + k * 64), acc[0], 0, 0, 0);
        if (nt > 1) acc[1] = __builtin_amdgcn_mfma_f32_16x16x32_bf16(afs[k], *(const v8s*)(rp1 + k * 64), acc[1], 0, 0, 0);
        if (nt > 2) acc[2] = __builtin_amdgcn_mfma_f32_16x16x32_bf16(afs[k], *(const v8s*)(rp2 + k * 64), acc[2], 0, 0, 0);
        if (nt > 3) acc[3] = __builtin_amdgcn_mfma_f32_16x16x32_bf16(afs[k], *(const v8s*)(rp3 + k * 64), acc[3], 0, 0, 0);
    }
    const int m0 = wave * 16 + g * 4;
    #pragma unroll
    for (int j = 0; j < 4; ++j) {
        const int l = j * 16 + nl;
        if (j < nt && l < L)
            *(v4f*)(Qf + (size_t)b * CB_STRIDE + (size_t)(row0 + l) * 256 + m0) = acc[j];
    }
}

__global__ __launch_bounds__(1024, 4)
void chain(const unsigned short* __restrict__ xb,
           const unsigned short* __restrict__ w2t,
           const unsigned short* __restrict__ w3t,
           const unsigned short* __restrict__ vwb,
           const float* __restrict__ b2, const float* __restrict__ b3,
           float* __restrict__ Qf, float* __restrict__ P)
{
    __shared__ __align__(16) char lds[2 * BUF];
    const int b = blockIdx.x;
    const int tid = threadIdx.x;
    const int wave = tid >> 6, lane = tid & 63, nl = lane & 15, g = lane >> 4;

    char* base = lds;

    // stage x into buf0
    {
        const unsigned short* src = xb + (size_t)b * 16384;
        #pragma unroll
        for (int i = 0; i < 2; ++i) {
            const int c = tid + i * 1024;
            const int r = c >> 5, cc = c & 31;
            const v8s v = *(const v8s*)(src + r * 256 + cc * 8);
            *(v8s*)(base + r * RS + cc * 16) = v;
        }
    }
    __syncthreads();

    // projections P[p][b][o][i] = vw[:, p*256 : (p+1)*256] * x
    for (int p = 0; p < 3; ++p) {
        v4f acc[4] = {{0,0,0,0},{0,0,0,0},{0,0,0,0},{0,0,0,0}};
        const unsigned short* Arow = vwb + (size_t)(wave * 16 + nl) * 768 + p * 256 + g * 8;
        v8s afs[8];
        #pragma unroll
        for (int k = 0; k < 8; ++k)
            afs[k] = *(const v8s*)(Arow + k * 32);
        #pragma unroll
        for (int k = 0; k < 8; ++k) {
            #pragma unroll
            for (int j = 0; j < 4; ++j) {
                const v8s bf = *(const v8s*)(base + (j * 16 + nl) * RS + k * 64 + g * 16);
                acc[j] = __builtin_amdgcn_mfma_f32_16x16x32_bf16(afs[k], bf, acc[j], 0, 0, 0);
            }
        }
        const int m0 = wave * 16 + g * 4;
        #pragma unroll
        for (int j = 0; j < 4; ++j) {
            float* po = P + (size_t)p * PPART + (size_t)b * 16384 + j * 16 + nl;
            #pragma unroll
            for (int r = 0; r < 4; ++r) po[(size_t)(m0 + r) * 64] = acc[j][r];
        }
    }

    // 31-step chain, ping-pong LDS buffers; Q segment after each step
    int cur = 0, i2 = 0, i3 = 0;
    for (int t = 0; t < NSTEP; ++t) {
        const int L = d_lens[t];
        char* inb  = base + cur * BUF;
        char* outb = base + (cur ^ 1) * BUF;
        if (t == 15 || t == 23) {
            conv_step<3, 2>(w3t + (size_t)i3 * 196608, b3 + i3 * 256,
                            inb, outb, L, wave, nl, g);
            ++i3;
        } else {
            conv_step<2, 1>(w2t + (size_t)i2 * 131072, b2 + i2 * 256,
                            inb, outb, L, wave, nl, g);
            ++i2;
        }
        __syncthreads();
        q_step(vwb, outb, Qf, b, d_cb[t], L, wave, nl, g);
        cur ^= 1;
    }
}

// out[b,o,i,j] = vis_b[o]                          (unset)
//             + Pl[b,o,i]+Pm[b,o,i]+Pr[b,o,i]      (diag)
//             + Pl[b,o,i]+Q[b,q,o]+Pr[b,o,j]       (set off-diag)
__global__ __launch_bounds__(256)
void final_k(const float* __restrict__ P, const float* __restrict__ Qb,
             const float* __restrict__ vb, float* __restrict__ out)
{
    const int b = blockIdx.x >> 6;
    const int i = blockIdx.x & 63;
    const int t = threadIdx.x;
    const int j = t & 63;
    const int os = t >> 6;

    __shared__ int qidx[64];
    if (t < 64) {
        const int d = t - i;
        int v = -1;
        if (t == i) v = -2;
        else if (d >= 1 && d <= 15) v = d_cb[d-1] + i;
        else if (d >= 17 && d <= 31 && (d & 1) && !(i & 1)) v = d_cb[15 + ((d-17)>>1)] + (i>>1);
        else if (d >= 35 && d <= 63 && ((d-35)&3)==0 && !(i&3)) v = d_cb[23 + ((d-35)>>2)] + (i>>2);
        qidx[t] = v;
    }
    __syncthreads();
    const int q = qidx[j];

    for (int oc = 0; oc < 64; ++oc) {
        const int o = oc * 4 + os;
        const float pl = P[(size_t)(b * 256 + o) * 64 + i];
        const float pm = P[524288u + (size_t)(b * 256 + o) * 64 + i];
        const float* pr = P + 1048576u + (size_t)(b * 256 + o) * 64;
        const float vbv = vb[o];
        float v;
        if (q == -2)      v = pl + pm + pr[i] + vbv;
        else if (q >= 0)  v = pl + Qb[(size_t)b * CB_STRIDE + (size_t)q * 256 + o] + pr[j] + vbv;
        else              v = vbv;
        out[(((size_t)b * 256 + o) * 64 + i) * 64 + j] = v;
    }
}

extern "C" void kernel_launch(void* const* d_in, const int* in_sizes, int n_in,
                              void* d_out, int out_size, void* d_ws, size_t ws_size,
                              hipStream_t stream)
{
    const float* x   = (const float*)d_in[0];
    const float* w2  = (const float*)d_in[1];
    const float* b2  = (const float*)d_in[2];
    const float* w3  = (const float*)d_in[3];
    const float* b3  = (const float*)d_in[4];
    const float* vw  = (const float*)d_in[5];
    const float* vb  = (const float*)d_in[6];
    float* out = (float*)d_out;

    // workspace: Q f32 34.08M | P f32 6.29M | xb 1.05M | w2t 7.60M | w3t 0.79M | vwb 0.39M
    char* w = (char*)d_ws;
    float*          Qf  = (float*)w;          w += (size_t)BB * CB_STRIDE * 4;
    float*          P   = (float*)w;          w += (size_t)3 * PPART * 4;
    unsigned short* xb  = (unsigned short*)w; w += (size_t)BB * 16384 * 2;
    unsigned short* w2t = (unsigned short*)w; w += (size_t)29 * 131072 * 2;
    unsigned short* w3t = (unsigned short*)w; w += (size_t)2 * 196608 * 2;
    unsigned short* vwb = (unsigned short*)w;

    prep<<<dim3(19200), 256, 0, stream>>>(x, w2, w3, vw, xb, w2t, w3t, vwb);
    chain<<<dim3(BB), 1024, 0, stream>>>(xb, w2t, w3t, vwb, b2, b3, Qf, P);
    final_k<<<dim3(BB * 64), 256, 0, stream>>>(P, Qf, vb, out);
}